// Round 19
// baseline (175.125 us; speedup 1.0000x reference)
//
#include <hip/hip_runtime.h>
#include <math.h>

#define N_NODES 50000
#define N_EDGES 800000
#define IN_DIM 128
#define OUT_DIM 16
#define N_HEADS 4
#define HID 64            // N_HEADS*OUT_DIM
#define AW_COLS 33        // 2*OUT_DIM+1
#define GN 56             // nodes per block (gemm): 4 waves x 14
#define GEMM_BLK ((N_NODES + GN - 1) / GN)             // 893
#define HE 16             // edges per thread (hist)
#define HBLK ((N_EDGES + 256 * HE - 1) / (256 * HE))   // 196
#define MAXDEG 64         // padded bucket width; deg~Poisson(16), max~35 (12 sigma margin)

// Fused kernel. Hist blocks FIRST (overlap, R16). R19: gemm uses 2-output
// register blocking — wave = 2 lane-halves x 32 o-slots; lane computes outputs
// {o2, o2+32} for its half's 7 nodes (wave = 14 nodes). One nv ds_read now
// feeds 8 FMAs (was 4), cutting the binding DS-issue pipe ~45%. Per-output FMA
// order, b[o] seed, and 16-lane alphas butterflies unchanged -> h/z bits
// identical to R18. LDS 61440 B (proven-safe class).
// NOTE (R7/R8): f64 MFMA produced zeros (wrong operand mapping) — shelved.
// NOTE (R10/R14): in-loop global reads for staging operands lose to bulk LDS
// staging; don't retry.
__global__ __launch_bounds__(256) void gemm_hist(
    const float* __restrict__ nodes, const float* __restrict__ W,
    const float* __restrict__ b, const float* __restrict__ attn_W,
    const float* __restrict__ attn_b, const float* __restrict__ edges,
    float* __restrict__ h, double* __restrict__ z_src, double* __restrict__ z_dst,
    const int* __restrict__ senders, const int* __restrict__ receivers,
    int* __restrict__ counts, int* __restrict__ srt_padded,
    double* __restrict__ Ssum) {
    __shared__ float sW[HID * IN_DIM];     // 32 KB, rotated-quad layout
    __shared__ float sN[GN * IN_DIM];      // 28 KB (gemm staging / hist red[])
    int t = threadIdx.x;

    if (blockIdx.x < HBLK) {
        // ---------------- hist + direct bucket-scatter (R17) ----------------
        double* red = (double*)sN;
        int base = blockIdx.x * 256 * HE + t;
        double sp = 0.0;
        #pragma unroll
        for (int j = 0; j < HE; ++j) {
            int e = base + j * 256;
            if (e < N_EDGES) {
                int r = receivers[e];
                int rank = atomicAdd(&counts[r], 1);            // 0..deg-1
                if (rank < MAXDEG)
                    srt_padded[r * MAXDEG + rank] = senders[e];
                sp += (double)edges[senders[e]];
            }
        }
        red[t] = sp;
        __syncthreads();
        for (int off = 128; off > 0; off >>= 1) {
            if (t < off) red[t] += red[t + off];
            __syncthreads();
        }
        if (t == 0) atomicAdd(Ssum, red[0]);
    } else {
        // ---------------- gemm body: 2-output blocking ----------------
        for (int i4 = t; i4 < HID * IN_DIM / 4; i4 += 256) {
            int o = i4 >> 5, kq = i4 & 31;
            float4 v = ((const float4*)W)[i4];
            *(float4*)&sW[o * IN_DIM + (((kq + o) & 31) << 2)] = v;
        }
        int node0 = (blockIdx.x - HBLK) * GN;
        for (int i4 = t; i4 < GN * IN_DIM / 4; i4 += 256) {   // 1792 quads
            int ln = i4 >> 5;
            int n = node0 + ln;
            float4 v = (n < N_NODES) ? ((const float4*)nodes)[(long long)n * (IN_DIM / 4) + (i4 & 31)]
                                     : make_float4(0.f, 0.f, 0.f, 0.f);
            *(float4*)&sN[i4 << 2] = v;
        }
        __syncthreads();
        int w = t >> 6, l = t & 63;
        int half = l >> 5;                 // lane-half -> node subgroup
        int o2 = l & 31;                   // outputs o2 and o2+32
        int nwbase = w * 14 + half * 7;    // local node base
        double acc0[7], acc1[7];
        double b0 = (double)b[o2], b1 = (double)b[o2 + 32];
        #pragma unroll
        for (int j = 0; j < 7; ++j) { acc0[j] = b0; acc1[j] = b1; }
        const float* wrow0 = &sW[o2 * IN_DIM];
        const float* wrow1 = &sW[(o2 + 32) * IN_DIM];
        const float* nbase = &sN[nwbase * IN_DIM];
        for (int kq = 0; kq < 32; ++kq) {
            int rot = ((kq + o2) & 31) << 2;   // storage rotation: same col for o2 and o2+32
            float4 wv0 = *(const float4*)&wrow0[rot];
            float4 wv1 = *(const float4*)&wrow1[rot];
            double w0x = (double)wv0.x, w0y = (double)wv0.y, w0z = (double)wv0.z, w0w = (double)wv0.w;
            double w1x = (double)wv1.x, w1y = (double)wv1.y, w1z = (double)wv1.z, w1w = (double)wv1.w;
            #pragma unroll
            for (int j = 0; j < 7; ++j) {
                float4 nv = *(const float4*)&nbase[j * IN_DIM + (kq << 2)];  // broadcast/half
                double nx = (double)nv.x, ny = (double)nv.y;
                double nz = (double)nv.z, nw = (double)nv.w;
                acc0[j] += w0x * nx; acc0[j] += w0y * ny;
                acc0[j] += w0z * nz; acc0[j] += w0w * nw;
                acc1[j] += w1x * nx; acc1[j] += w1y * ny;
                acc1[j] += w1z * nz; acc1[j] += w1w * nw;
            }
        }
        int hd0 = o2 >> 4, d = o2 & 15;    // heads: hd0 (out0), hd0+2 (out1)
        int hd1 = hd0 + 2;
        double aw00 = (double)attn_W[hd0 * AW_COLS + d];
        double aw01 = (double)attn_W[hd0 * AW_COLS + OUT_DIM + d];
        double aw10 = (double)attn_W[hd1 * AW_COLS + d];
        double aw11 = (double)attn_W[hd1 * AW_COLS + OUT_DIM + d];
        double wE0 = (double)attn_W[hd0 * AW_COLS + 2 * OUT_DIM];
        double wE1 = (double)attn_W[hd1 * AW_COLS + 2 * OUT_DIM];
        double bb0 = (double)attn_b[hd0], bb1 = (double)attn_b[hd1];
        #pragma unroll
        for (int j = 0; j < 7; ++j) {
            int n = node0 + nwbase + j;    // uniform per lane-half
            if (n >= N_NODES) continue;
            float hf0 = (float)acc0[j];
            float hf1 = (float)acc1[j];
            h[(long long)n * HID + o2] = hf0;
            h[(long long)n * HID + o2 + 32] = hf1;
            double c00 = (double)hf0 * aw00;   // a_src part, head hd0
            double c01 = (double)hf0 * aw01;   // a_dst part, head hd0
            double c10 = (double)hf1 * aw10;   // a_src part, head hd1
            double c11 = (double)hf1 * aw11;   // a_dst part, head hd1
            #pragma unroll
            for (int k = 1; k <= 8; k <<= 1) {
                c00 += __shfl_xor(c00, k, 64);
                c01 += __shfl_xor(c01, k, 64);
                c10 += __shfl_xor(c10, k, 64);
                c11 += __shfl_xor(c11, k, 64);
            }
            if (d == 0) {
                double se = (double)edges[n];
                z_src[n * N_HEADS + hd0] = c00 + se * wE0;
                z_dst[n * N_HEADS + hd0] = c01 + bb0;
                z_src[n * N_HEADS + hd1] = c10 + se * wE1;
                z_dst[n * N_HEADS + hd1] = c11 + bb1;
            }
        }
    }
}

// One wave per node. Lane = (head hd=lane>>4, slot q=lane&15); lane evaluates
// edges q+16j for ITS head only: y = leaky(z_src[s][hd] + z_dst[node][hd]) —
// single gather. s[] kept in registers; survivors resolved via shuffles.
// Segmented 16-lane reductions; ballot-compressed accumulate.
__global__ __launch_bounds__(256) void node_fused(
    const float* __restrict__ h, const double* __restrict__ z_src,
    const double* __restrict__ z_dst,
    const int* __restrict__ srt_padded, const int* __restrict__ counts,
    const double* __restrict__ Ssum, float* __restrict__ out) {
    int node = blockIdx.x * 4 + (threadIdx.x >> 6);
    int lane = threadIdx.x & 63;
    if (node >= N_NODES) return;
    int hd = lane >> 4, q = lane & 15;
    int deg = counts[node];
    if (deg > MAXDEG) deg = MAXDEG;      // unreachable for this graph (12 sigma)
    long long obase = (long long)node * HID + lane;
    if (deg <= 0) { out[obase] = 0.f; return; }
    const int* srow = srt_padded + node * MAXDEG;

    double S = 4.0 * Ssum[0];                       // sent_e tiled over heads
    double zdn = z_dst[node * N_HEADS + hd];
    float den = 0.f, acc = 0.f;

    int s[4];
    float y[4], ev[4];
    #pragma unroll
    for (int j = 0; j < 4; ++j) {
        int ei = q + 16 * j;
        y[j] = -INFINITY;
        s[j] = 0;
        if (ei < deg) {
            s[j] = srow[ei];
            double yy = z_src[(long long)s[j] * N_HEADS + hd] + zdn;
            yy = yy > 0.0 ? yy : 0.01 * yy;         // leaky (fp64, then round)
            y[j] = (float)yy;
        }
    }
    float mv = fmaxf(fmaxf(y[0], y[1]), fmaxf(y[2], y[3]));
    #pragma unroll
    for (int k = 1; k <= 8; k <<= 1)
        mv = fmaxf(mv, __shfl_xor(mv, k, 64));
    float m_run = mv;
    float dsum = 0.f;
    #pragma unroll
    for (int j = 0; j < 4; ++j) {
        ev[j] = (y[j] == -INFINITY) ? 0.f
              : __expf((float)(S * ((double)y[j] - (double)m_run)));
        dsum += ev[j];
    }
    #pragma unroll
    for (int k = 1; k <= 8; k <<= 1)
        dsum += __shfl_xor(dsum, k, 64);
    den += dsum;
    #pragma unroll
    for (int j = 0; j < 4; ++j) {
        unsigned long long mk = __ballot(ev[j] != 0.f);
        unsigned um = (unsigned)((mk | (mk >> 16) | (mk >> 32) | (mk >> 48)) & 0xFFFFull);
        while (um) {
            int qq = __builtin_ctz(um);
            um &= um - 1;
            int src = (lane & 48) | qq;                 // own head's copy
            float evv = __shfl(ev[j], src, 64);
            int sj = __shfl(s[j], src, 64);
            if (evv != 0.f)
                acc = fmaf(evv, h[(long long)sj * HID + lane], acc);
        }
    }
    float r = (den > 0.f) ? acc / den : 0.f;
    out[obase] = r > 0.f ? r : 0.01f * r;
}

static inline char* ws_take(char*& p, size_t bytes) {
    char* cur = p;
    p += (bytes + 255) & ~(size_t)255;   // keep every buffer 256B-aligned
    return cur;
}

extern "C" void kernel_launch(void* const* d_in, const int* in_sizes, int n_in,
                              void* d_out, int out_size, void* d_ws, size_t ws_size,
                              hipStream_t stream) {
    const float* nodes     = (const float*)d_in[0];
    const float* edges     = (const float*)d_in[1];
    const int*   senders   = (const int*)d_in[2];
    const int*   receivers = (const int*)d_in[3];
    const float* W         = (const float*)d_in[4];
    const float* b         = (const float*)d_in[5];
    const float* attn_W    = (const float*)d_in[6];
    const float* attn_b    = (const float*)d_in[7];
    float* out = (float*)d_out;

    char* p = (char*)d_ws;
    float*  h          = (float*)ws_take(p, sizeof(float) * N_NODES * HID);
    double* z_src      = (double*)ws_take(p, sizeof(double) * N_NODES * N_HEADS);
    double* z_dst      = (double*)ws_take(p, sizeof(double) * N_NODES * N_HEADS);
    int*    counts     = (int*)ws_take(p, sizeof(int) * N_NODES);   // contiguous with
    char*   zpad       = ws_take(p, 256);                           // Ssum: one memset
    double* Ssum       = (double*)zpad;
    int*    srt_padded = (int*)ws_take(p, sizeof(int) * (size_t)N_NODES * MAXDEG);

    // counts (256B-rounded) + the Ssum pad in one memset; srt_padded needs no init
    hipMemsetAsync(counts, 0, ((sizeof(int) * N_NODES + 255) & ~(size_t)255) + 256, stream);

    gemm_hist<<<HBLK + GEMM_BLK, 256, 0, stream>>>(
        nodes, W, b, attn_W, attn_b, edges, h, z_src, z_dst,
        senders, receivers, counts, srt_padded, Ssum);
    node_fused<<<(N_NODES + 3) / 4, 256, 0, stream>>>(
        h, z_src, z_dst, srt_padded, counts, Ssum, out);
}

// Round 20
// 162.736 us; speedup vs baseline: 1.0761x; 1.0761x over previous
//
#include <hip/hip_runtime.h>
#include <math.h>

#define N_NODES 50000
#define N_EDGES 800000
#define IN_DIM 128
#define OUT_DIM 16
#define N_HEADS 4
#define HID 64            // N_HEADS*OUT_DIM
#define AW_COLS 33        // 2*OUT_DIM+1
#define GN 32             // nodes per block (gemm): 4 waves x 8
#define GEMM_BLK ((N_NODES + GN - 1) / GN)             // 1563
#define HE 16             // edges per thread (hist)
#define HBLK ((N_EDGES + 256 * HE - 1) / (256 * HE))   // 196
#define MAXDEG 64         // padded bucket width; deg~Poisson(16), max~35 (12 sigma margin)

// Fused kernel. Hist blocks FIRST (overlap, R16). R20: 2-output register
// blocking (R19-verified numerics) at the R18 resource footprint — GN=32 keeps
// LDS at 49152 (3 blocks/CU) and acc count at 8 (VGPR ~76), fixing R19's
// occupancy cliff (61K LDS + 88 VGPR -> 17% occ, regressed). Wave = 2
// lane-halves x 32 o-slots; lane computes outputs {o2,o2+32} for its half's 4
// nodes. DS instrs/kq: 6 (2 wv + 4 nv) vs R18's 9 for the same 8-node x 64-out
// coverage -> 33% cut of the binding DS pipe at unchanged occupancy.
// NOTE (R7/R8): f64 MFMA produced zeros (wrong operand mapping) — shelved.
// NOTE (R10/R14): in-loop global reads for staging operands lose to bulk LDS
// staging; don't retry.
__global__ __launch_bounds__(256) void gemm_hist(
    const float* __restrict__ nodes, const float* __restrict__ W,
    const float* __restrict__ b, const float* __restrict__ attn_W,
    const float* __restrict__ attn_b, const float* __restrict__ edges,
    float* __restrict__ h, double* __restrict__ z_src, double* __restrict__ z_dst,
    const int* __restrict__ senders, const int* __restrict__ receivers,
    int* __restrict__ counts, int* __restrict__ srt_padded,
    double* __restrict__ Ssum) {
    __shared__ float sW[HID * IN_DIM];     // 32 KB, rotated-quad layout
    __shared__ float sN[GN * IN_DIM];      // 16 KB (gemm staging / hist red[])
    int t = threadIdx.x;

    if (blockIdx.x < HBLK) {
        // ---------------- hist + direct bucket-scatter (R17) ----------------
        double* red = (double*)sN;
        int base = blockIdx.x * 256 * HE + t;
        double sp = 0.0;
        #pragma unroll
        for (int j = 0; j < HE; ++j) {
            int e = base + j * 256;
            if (e < N_EDGES) {
                int r = receivers[e];
                int rank = atomicAdd(&counts[r], 1);            // 0..deg-1
                if (rank < MAXDEG)
                    srt_padded[r * MAXDEG + rank] = senders[e];
                sp += (double)edges[senders[e]];
            }
        }
        red[t] = sp;
        __syncthreads();
        for (int off = 128; off > 0; off >>= 1) {
            if (t < off) red[t] += red[t + off];
            __syncthreads();
        }
        if (t == 0) atomicAdd(Ssum, red[0]);
    } else {
        // ---------------- gemm body: 2-output blocking, GN=32 ----------------
        for (int i4 = t; i4 < HID * IN_DIM / 4; i4 += 256) {
            int o = i4 >> 5, kq = i4 & 31;
            float4 v = ((const float4*)W)[i4];
            *(float4*)&sW[o * IN_DIM + (((kq + o) & 31) << 2)] = v;
        }
        int node0 = (blockIdx.x - HBLK) * GN;
        for (int i4 = t; i4 < GN * IN_DIM / 4; i4 += 256) {   // 1024 quads
            int ln = i4 >> 5;
            int n = node0 + ln;
            float4 v = (n < N_NODES) ? ((const float4*)nodes)[(long long)n * (IN_DIM / 4) + (i4 & 31)]
                                     : make_float4(0.f, 0.f, 0.f, 0.f);
            *(float4*)&sN[i4 << 2] = v;
        }
        __syncthreads();
        int w = t >> 6, l = t & 63;
        int half = l >> 5;                 // lane-half -> node subgroup
        int o2 = l & 31;                   // outputs o2 and o2+32
        int nwbase = w * 8 + half * 4;     // local node base (4 nodes per half)
        double acc0[4], acc1[4];
        double b0 = (double)b[o2], b1 = (double)b[o2 + 32];
        #pragma unroll
        for (int j = 0; j < 4; ++j) { acc0[j] = b0; acc1[j] = b1; }
        const float* wrow0 = &sW[o2 * IN_DIM];
        const float* wrow1 = &sW[(o2 + 32) * IN_DIM];
        const float* nbase = &sN[nwbase * IN_DIM];
        for (int kq = 0; kq < 32; ++kq) {
            int rot = ((kq + o2) & 31) << 2;   // same rot for o2 and o2+32 (mod 32)
            float4 wv0 = *(const float4*)&wrow0[rot];
            float4 wv1 = *(const float4*)&wrow1[rot];
            double w0x = (double)wv0.x, w0y = (double)wv0.y, w0z = (double)wv0.z, w0w = (double)wv0.w;
            double w1x = (double)wv1.x, w1y = (double)wv1.y, w1z = (double)wv1.z, w1w = (double)wv1.w;
            #pragma unroll
            for (int j = 0; j < 4; ++j) {
                float4 nv = *(const float4*)&nbase[j * IN_DIM + (kq << 2)];  // broadcast/half
                double nx = (double)nv.x, ny = (double)nv.y;
                double nz = (double)nv.z, nw = (double)nv.w;
                acc0[j] += w0x * nx; acc0[j] += w0y * ny;
                acc0[j] += w0z * nz; acc0[j] += w0w * nw;
                acc1[j] += w1x * nx; acc1[j] += w1y * ny;
                acc1[j] += w1z * nz; acc1[j] += w1w * nw;
            }
        }
        int hd0 = o2 >> 4, d = o2 & 15;    // heads: hd0 (out0), hd0+2 (out1)
        int hd1 = hd0 + 2;
        double aw00 = (double)attn_W[hd0 * AW_COLS + d];
        double aw01 = (double)attn_W[hd0 * AW_COLS + OUT_DIM + d];
        double aw10 = (double)attn_W[hd1 * AW_COLS + d];
        double aw11 = (double)attn_W[hd1 * AW_COLS + OUT_DIM + d];
        double wE0 = (double)attn_W[hd0 * AW_COLS + 2 * OUT_DIM];
        double wE1 = (double)attn_W[hd1 * AW_COLS + 2 * OUT_DIM];
        double bb0 = (double)attn_b[hd0], bb1 = (double)attn_b[hd1];
        #pragma unroll
        for (int j = 0; j < 4; ++j) {
            int n = node0 + nwbase + j;    // uniform per lane-half
            if (n >= N_NODES) continue;
            float hf0 = (float)acc0[j];
            float hf1 = (float)acc1[j];
            h[(long long)n * HID + o2] = hf0;
            h[(long long)n * HID + o2 + 32] = hf1;
            double c00 = (double)hf0 * aw00;   // a_src part, head hd0
            double c01 = (double)hf0 * aw01;   // a_dst part, head hd0
            double c10 = (double)hf1 * aw10;   // a_src part, head hd1
            double c11 = (double)hf1 * aw11;   // a_dst part, head hd1
            #pragma unroll
            for (int k = 1; k <= 8; k <<= 1) {
                c00 += __shfl_xor(c00, k, 64);
                c01 += __shfl_xor(c01, k, 64);
                c10 += __shfl_xor(c10, k, 64);
                c11 += __shfl_xor(c11, k, 64);
            }
            if (d == 0) {
                double se = (double)edges[n];
                z_src[n * N_HEADS + hd0] = c00 + se * wE0;
                z_dst[n * N_HEADS + hd0] = c01 + bb0;
                z_src[n * N_HEADS + hd1] = c10 + se * wE1;
                z_dst[n * N_HEADS + hd1] = c11 + bb1;
            }
        }
    }
}

// One wave per node. Lane = (head hd=lane>>4, slot q=lane&15); lane evaluates
// edges q+16j for ITS head only: y = leaky(z_src[s][hd] + z_dst[node][hd]) —
// single gather. s[] kept in registers; survivors resolved via shuffles.
// Segmented 16-lane reductions; ballot-compressed accumulate.
__global__ __launch_bounds__(256) void node_fused(
    const float* __restrict__ h, const double* __restrict__ z_src,
    const double* __restrict__ z_dst,
    const int* __restrict__ srt_padded, const int* __restrict__ counts,
    const double* __restrict__ Ssum, float* __restrict__ out) {
    int node = blockIdx.x * 4 + (threadIdx.x >> 6);
    int lane = threadIdx.x & 63;
    if (node >= N_NODES) return;
    int hd = lane >> 4, q = lane & 15;
    int deg = counts[node];
    if (deg > MAXDEG) deg = MAXDEG;      // unreachable for this graph (12 sigma)
    long long obase = (long long)node * HID + lane;
    if (deg <= 0) { out[obase] = 0.f; return; }
    const int* srow = srt_padded + node * MAXDEG;

    double S = 4.0 * Ssum[0];                       // sent_e tiled over heads
    double zdn = z_dst[node * N_HEADS + hd];
    float den = 0.f, acc = 0.f;

    int s[4];
    float y[4], ev[4];
    #pragma unroll
    for (int j = 0; j < 4; ++j) {
        int ei = q + 16 * j;
        y[j] = -INFINITY;
        s[j] = 0;
        if (ei < deg) {
            s[j] = srow[ei];
            double yy = z_src[(long long)s[j] * N_HEADS + hd] + zdn;
            yy = yy > 0.0 ? yy : 0.01 * yy;         // leaky (fp64, then round)
            y[j] = (float)yy;
        }
    }
    float mv = fmaxf(fmaxf(y[0], y[1]), fmaxf(y[2], y[3]));
    #pragma unroll
    for (int k = 1; k <= 8; k <<= 1)
        mv = fmaxf(mv, __shfl_xor(mv, k, 64));
    float m_run = mv;
    float dsum = 0.f;
    #pragma unroll
    for (int j = 0; j < 4; ++j) {
        ev[j] = (y[j] == -INFINITY) ? 0.f
              : __expf((float)(S * ((double)y[j] - (double)m_run)));
        dsum += ev[j];
    }
    #pragma unroll
    for (int k = 1; k <= 8; k <<= 1)
        dsum += __shfl_xor(dsum, k, 64);
    den += dsum;
    #pragma unroll
    for (int j = 0; j < 4; ++j) {
        unsigned long long mk = __ballot(ev[j] != 0.f);
        unsigned um = (unsigned)((mk | (mk >> 16) | (mk >> 32) | (mk >> 48)) & 0xFFFFull);
        while (um) {
            int qq = __builtin_ctz(um);
            um &= um - 1;
            int src = (lane & 48) | qq;                 // own head's copy
            float evv = __shfl(ev[j], src, 64);
            int sj = __shfl(s[j], src, 64);
            if (evv != 0.f)
                acc = fmaf(evv, h[(long long)sj * HID + lane], acc);
        }
    }
    float r = (den > 0.f) ? acc / den : 0.f;
    out[obase] = r > 0.f ? r : 0.01f * r;
}

static inline char* ws_take(char*& p, size_t bytes) {
    char* cur = p;
    p += (bytes + 255) & ~(size_t)255;   // keep every buffer 256B-aligned
    return cur;
}

extern "C" void kernel_launch(void* const* d_in, const int* in_sizes, int n_in,
                              void* d_out, int out_size, void* d_ws, size_t ws_size,
                              hipStream_t stream) {
    const float* nodes     = (const float*)d_in[0];
    const float* edges     = (const float*)d_in[1];
    const int*   senders   = (const int*)d_in[2];
    const int*   receivers = (const int*)d_in[3];
    const float* W         = (const float*)d_in[4];
    const float* b         = (const float*)d_in[5];
    const float* attn_W    = (const float*)d_in[6];
    const float* attn_b    = (const float*)d_in[7];
    float* out = (float*)d_out;

    char* p = (char*)d_ws;
    float*  h          = (float*)ws_take(p, sizeof(float) * N_NODES * HID);
    double* z_src      = (double*)ws_take(p, sizeof(double) * N_NODES * N_HEADS);
    double* z_dst      = (double*)ws_take(p, sizeof(double) * N_NODES * N_HEADS);
    int*    counts     = (int*)ws_take(p, sizeof(int) * N_NODES);   // contiguous with
    char*   zpad       = ws_take(p, 256);                           // Ssum: one memset
    double* Ssum       = (double*)zpad;
    int*    srt_padded = (int*)ws_take(p, sizeof(int) * (size_t)N_NODES * MAXDEG);

    // counts (256B-rounded) + the Ssum pad in one memset; srt_padded needs no init
    hipMemsetAsync(counts, 0, ((sizeof(int) * N_NODES + 255) & ~(size_t)255) + 256, stream);

    gemm_hist<<<HBLK + GEMM_BLK, 256, 0, stream>>>(
        nodes, W, b, attn_W, attn_b, edges, h, z_src, z_dst,
        senders, receivers, counts, srt_padded, Ssum);
    node_fused<<<(N_NODES + 3) / 4, 256, 0, stream>>>(
        h, z_src, z_dst, srt_padded, counts, Ssum, out);
}